// Round 1
// baseline (85.942 us; speedup 1.0000x reference)
//
#include <hip/hip_runtime.h>

typedef unsigned short ushort_t;
typedef __attribute__((ext_vector_type(8))) __bf16 bf16x8;
typedef __attribute__((ext_vector_type(8))) short short8_t;
typedef __attribute__((ext_vector_type(4))) float f32x4;

#define C127 (127.0f / 128.0f)

__device__ inline ushort_t f2bf(float f) {
  unsigned u = __builtin_bit_cast(unsigned, f);
  u += 0x7fffu + ((u >> 16) & 1u);
  return (ushort_t)(u >> 16);
}

__device__ inline bf16x8 ldfrag(const ushort_t* p) {
  return __builtin_bit_cast(bf16x8, *(const short8_t*)p);
}

__device__ inline f32x4 mfma16(bf16x8 a, bf16x8 b, f32x4 c) {
  return __builtin_amdgcn_mfma_f32_16x16x32_bf16(a, b, c, 0, 0, 0);
}

// XOR swizzle for 64-elem-wide bf16 LDS tiles: col is elem offset (multiple of 8)
__device__ inline int swz(int row, int col) {
  return row * 64 + (col ^ ((row & 7) << 3));
}
// for 1024-elem-wide tile (W1)
__device__ inline int swzW(int row, int col) {
  return row * 1024 + (col ^ ((row & 7) << 3));
}

// ---------------- prep: weights -> bf16 ----------------
__global__ __launch_bounds__(256) void k_wprep(
    const float* Wp, const float* Wmi, const float* Wma, const float* Wd,
    const float* W1p, const float* W1mi, const float* W1ma, const float* W1d,
    const float* Wop, const float* Womi, const float* Woma, const float* Wod,
    const float* bop, const float* bomi, const float* boma, const float* bod,
    const float* Wc,
    ushort_t* wft, ushort_t* w1b, ushort_t* bfm, float* biassum)
{
  int i = blockIdx.x * 256 + threadIdx.x;
  const int NW = 2359296, NW1 = 65536, NBF = 229376;
  if (i < NW) {
    const float* src; int j;
    if (i < 262144)       { src = Wp;  j = i; }
    else if (i < 786432)  { src = Wmi; j = i - 262144; }
    else if (i < 1572864) { src = Wma; j = i - 786432; }
    else                  { src = Wd;  j = i - 1572864; }
    wft[i] = f2bf(src[j]);
  } else if (i < NW + NW1) {
    int j = i - NW;
    int s = j >> 14, jj = j & 16383;
    const float* src = (s == 0) ? W1p : (s == 1) ? W1mi : (s == 2) ? W1ma : W1d;
    w1b[j] = f2bf(src[jj]);
  } else if (i < NW + NW1 + NBF) {
    int j = i - NW - NW1;
    int n = j / 896, c = j - n * 896;
    float v;
    if (c < 128) {
      int s = c >> 5, jj = c & 31;
      const float* src = (s == 0) ? Wop : (s == 1) ? Womi : (s == 2) ? Woma : Wod;
      v = src[n * 32 + jj];
    } else {
      v = Wc[n * 768 + (c - 128)];
    }
    bfm[j] = f2bf(v);
  } else if (i < NW + NW1 + NBF + 256) {
    int n = i - NW - NW1 - NBF;
    biassum[n] = bop[n] + bomi[n] + boma[n] + bod[n];
  }
}

// ---------------- prep: gather + convert x ----------------
__global__ __launch_bounds__(128) void k_xprep(
    const float* __restrict__ x,
    const int* __restrict__ pawn, const int* __restrict__ minor,
    const int* __restrict__ major, const int* __restrict__ diag,
    ushort_t* __restrict__ xsb, ushort_t* __restrict__ xb)
{
  int row = blockIdx.y;
  int c = blockIdx.x * 128 + threadIdx.x;  // 0..1919
  const float* xr = x + (size_t)row * 768;
  if (c < 1152) {
    int src;
    if (c < 128)      src = pawn[c];
    else if (c < 384) src = minor[c - 128];
    else if (c < 768) src = major[c - 384];
    else              src = diag[c - 768];
    xsb[(size_t)row * 1152 + c] = f2bf(xr[src]);
  } else {
    int cc = c - 1152;
    xb[(size_t)row * 768 + cc] = f2bf(xr[cc]);
  }
}

// ---------------- ft GEMM + activation ----------------
struct FtP {
  const ushort_t* xsb;
  const ushort_t* wft;
  ushort_t* inter;
  const float* bft0; const float* bft1; const float* bft2; const float* bft3;
};

__global__ __launch_bounds__(256) void k_ft(FtP p) {
  int s = blockIdx.z;
  int d, koff, woff; const float* bft;
  if (s == 0)      { d = 128; koff = 0;   woff = 0;       bft = p.bft0; }
  else if (s == 1) { d = 256; koff = 128; woff = 262144;  bft = p.bft1; }
  else if (s == 2) { d = 384; koff = 384; woff = 786432;  bft = p.bft2; }
  else             { d = 384; koff = 768; woff = 1572864; bft = p.bft3; }

  int row0 = blockIdx.y * 128;
  int nb = blockIdx.x;           // 16 tiles of 64 cols (paired with +1024)
  int tid = threadIdx.x;
  int lane = tid & 63, wid = tid >> 6;
  int wr = wid >> 1, wc = wid & 1;
  int lr = lane & 15, lk = (lane >> 4) * 8, lrow = (lane >> 4) * 4;

  const ushort_t* A  = p.xsb + (size_t)row0 * 1152 + koff;
  const ushort_t* B1 = p.wft + woff + (size_t)(nb * 64) * d;
  const ushort_t* B2 = p.wft + woff + (size_t)(nb * 64 + 1024) * d;

  __shared__ ushort_t lA[128 * 64];
  __shared__ ushort_t lB[2][64 * 64];

  const f32x4 fz = {0.f, 0.f, 0.f, 0.f};
  f32x4 acc[2][4][2];
  for (int h = 0; h < 2; ++h)
    for (int m = 0; m < 4; ++m)
      for (int n = 0; n < 2; ++n) acc[h][m][n] = fz;

  int sr = tid >> 3, sc = (tid & 7) * 8;
  for (int k0 = 0; k0 < d; k0 += 64) {
    __syncthreads();
    for (int pp = 0; pp < 4; ++pp) {
      int row = sr + pp * 32;
      *(short8_t*)&lA[swz(row, sc)] =
          *(const short8_t*)(A + (size_t)row * 1152 + k0 + sc);
    }
    for (int pp = 0; pp < 2; ++pp) {
      int row = sr + pp * 32;
      *(short8_t*)&lB[0][swz(row, sc)] =
          *(const short8_t*)(B1 + (size_t)row * d + k0 + sc);
      *(short8_t*)&lB[1][swz(row, sc)] =
          *(const short8_t*)(B2 + (size_t)row * d + k0 + sc);
    }
    __syncthreads();
    for (int kk = 0; kk < 64; kk += 32) {
      bf16x8 a[4], b[2][2];
      for (int m = 0; m < 4; ++m)
        a[m] = ldfrag(&lA[swz(wr * 64 + m * 16 + lr, kk + lk)]);
      for (int h = 0; h < 2; ++h)
        for (int n = 0; n < 2; ++n)
          b[h][n] = ldfrag(&lB[h][swz(wc * 32 + n * 16 + lr, kk + lk)]);
      for (int h = 0; h < 2; ++h)
        for (int m = 0; m < 4; ++m)
          for (int n = 0; n < 2; ++n)
            acc[h][m][n] = mfma16(a[m], b[h][n], acc[h][m][n]);
    }
  }

  ushort_t* ip = p.inter + ((size_t)s * 4096 + row0) * 1024 + nb * 64;
  for (int m = 0; m < 4; ++m)
    for (int n = 0; n < 2; ++n) {
      int col = wc * 32 + n * 16 + lr;
      float bb1 = bft[nb * 64 + col];
      float bb2 = bft[1024 + nb * 64 + col];
      for (int r = 0; r < 4; ++r) {
        int rowl = wr * 64 + m * 16 + lrow + r;
        float v = (acc[0][m][n][r] + bb1) * (acc[1][m][n][r] + bb2) * C127;
        ip[(size_t)rowl * 1024 + col] = f2bf(v);
      }
    }
}

// ---------------- W1 stage + cat/clip ----------------
__global__ __launch_bounds__(256) void k_w1(
    const ushort_t* __restrict__ inter, const ushort_t* __restrict__ w1b,
    ushort_t* __restrict__ cat,
    const float* b1p, const float* b1mi, const float* b1ma, const float* b1d)
{
  int s = blockIdx.y;
  const float* b1 = (s == 0) ? b1p : (s == 1) ? b1mi : (s == 2) ? b1ma : b1d;
  int row0 = blockIdx.x * 128;
  int tid = threadIdx.x;
  int lane = tid & 63, w = tid >> 6;
  int lr = lane & 15, lk = (lane >> 4) * 8, lrow = (lane >> 4) * 4;

  __shared__ ushort_t lB[16 * 1024];
  __shared__ ushort_t lA[128 * 64];

  const ushort_t* w1 = w1b + s * 16384;
  for (int pp = 0; pp < 8; ++pp) {
    int e = (pp * 256 + tid) * 8;
    int row = e >> 10, col = e & 1023;
    *(short8_t*)&lB[swzW(row, col)] = *(const short8_t*)(w1 + e);
  }

  const ushort_t* Ab = inter + ((size_t)s * 4096 + row0) * 1024;
  const f32x4 fz = {0.f, 0.f, 0.f, 0.f};
  f32x4 acc[2]; acc[0] = fz; acc[1] = fz;
  int sr = tid >> 3, sc = (tid & 7) * 8;
  for (int k0 = 0; k0 < 1024; k0 += 64) {
    __syncthreads();
    for (int pp = 0; pp < 4; ++pp) {
      int row = sr + pp * 32;
      *(short8_t*)&lA[swz(row, sc)] =
          *(const short8_t*)(Ab + (size_t)row * 1024 + k0 + sc);
    }
    __syncthreads();
    for (int kk = 0; kk < 64; kk += 32) {
      bf16x8 bfr = ldfrag(&lB[swzW(lr, k0 + kk + lk)]);
      for (int m = 0; m < 2; ++m) {
        bf16x8 afr = ldfrag(&lA[swz(w * 32 + m * 16 + lr, kk + lk)]);
        acc[m] = mfma16(afr, bfr, acc[m]);
      }
    }
  }

  float b1v = b1[lr];
  for (int m = 0; m < 2; ++m)
    for (int r = 0; r < 4; ++r) {
      int rowl = w * 32 + m * 16 + lrow + r;
      float f = acc[m][r] + b1v;
      float cf = fminf(fmaxf(f, 0.f), 1.f);
      float cs = fminf(f * f * C127, 1.f);
      size_t o = (size_t)(row0 + rowl) * 128 + s * 32 + lr;
      cat[o] = f2bf(cf);
      cat[o + 16] = f2bf(cs);
    }
}

// ---------------- final GEMM: [cat | x] @ [WoAll | Wc]^T + biassum ----------------
__global__ __launch_bounds__(256) void k_out(
    const ushort_t* __restrict__ cat, const ushort_t* __restrict__ xb,
    const ushort_t* __restrict__ bfm, const float* __restrict__ biassum,
    float* __restrict__ out)
{
  int row0 = blockIdx.y * 128;
  int nb = blockIdx.x;  // 0..3, 64 cols each
  int tid = threadIdx.x;
  int lane = tid & 63, wid = tid >> 6;
  int wr = wid >> 1, wc = wid & 1;
  int lr = lane & 15, lk = (lane >> 4) * 8, lrow = (lane >> 4) * 4;

  __shared__ ushort_t lA[128 * 64];
  __shared__ ushort_t lB[64 * 64];

  const f32x4 fz = {0.f, 0.f, 0.f, 0.f};
  f32x4 acc[4][2];
  for (int m = 0; m < 4; ++m)
    for (int n = 0; n < 2; ++n) acc[m][n] = fz;

  int sr = tid >> 3, sc = (tid & 7) * 8;
  for (int k0 = 0; k0 < 896; k0 += 64) {
    const ushort_t* Asrc; int lda;
    if (k0 < 128) { Asrc = cat + (size_t)row0 * 128 + k0; lda = 128; }
    else          { Asrc = xb + (size_t)row0 * 768 + (k0 - 128); lda = 768; }
    __syncthreads();
    for (int pp = 0; pp < 4; ++pp) {
      int row = sr + pp * 32;
      *(short8_t*)&lA[swz(row, sc)] =
          *(const short8_t*)(Asrc + (size_t)row * lda + sc);
    }
    for (int pp = 0; pp < 2; ++pp) {
      int row = sr + pp * 32;
      *(short8_t*)&lB[swz(row, sc)] =
          *(const short8_t*)(bfm + (size_t)(nb * 64 + row) * 896 + k0 + sc);
    }
    __syncthreads();
    for (int kk = 0; kk < 64; kk += 32) {
      bf16x8 a[4], b[2];
      for (int m = 0; m < 4; ++m)
        a[m] = ldfrag(&lA[swz(wr * 64 + m * 16 + lr, kk + lk)]);
      for (int n = 0; n < 2; ++n)
        b[n] = ldfrag(&lB[swz(wc * 32 + n * 16 + lr, kk + lk)]);
      for (int m = 0; m < 4; ++m)
        for (int n = 0; n < 2; ++n)
          acc[m][n] = mfma16(a[m], b[n], acc[m][n]);
    }
  }

  for (int m = 0; m < 4; ++m)
    for (int n = 0; n < 2; ++n) {
      int col = nb * 64 + wc * 32 + n * 16 + lr;
      float bs = biassum[col];
      for (int r = 0; r < 4; ++r) {
        int rowl = wr * 64 + m * 16 + lrow + r;
        out[(size_t)(row0 + rowl) * 256 + col] = acc[m][n][r] + bs;
      }
    }
}

extern "C" void kernel_launch(void* const* d_in, const int* in_sizes, int n_in,
                              void* d_out, int out_size, void* d_ws, size_t ws_size,
                              hipStream_t stream)
{
  const float* x     = (const float*)d_in[0];
  const int* pawn    = (const int*)d_in[1];
  const int* minor   = (const int*)d_in[2];
  const int* major   = (const int*)d_in[3];
  const int* diag    = (const int*)d_in[4];
  const float* pWft  = (const float*)d_in[5];   const float* pbft  = (const float*)d_in[6];
  const float* pW1   = (const float*)d_in[7];   const float* pb1   = (const float*)d_in[8];
  const float* pWo   = (const float*)d_in[9];   const float* pbo   = (const float*)d_in[10];
  const float* miWft = (const float*)d_in[11];  const float* mibft = (const float*)d_in[12];
  const float* miW1  = (const float*)d_in[13];  const float* mib1  = (const float*)d_in[14];
  const float* miWo  = (const float*)d_in[15];  const float* mibo  = (const float*)d_in[16];
  const float* maWft = (const float*)d_in[17];  const float* mabft = (const float*)d_in[18];
  const float* maW1  = (const float*)d_in[19];  const float* mab1  = (const float*)d_in[20];
  const float* maWo  = (const float*)d_in[21];  const float* mabo  = (const float*)d_in[22];
  const float* dWft  = (const float*)d_in[23];  const float* dbft  = (const float*)d_in[24];
  const float* dW1   = (const float*)d_in[25];  const float* db1   = (const float*)d_in[26];
  const float* dWo   = (const float*)d_in[27];  const float* dbo   = (const float*)d_in[28];
  const float* Wc    = (const float*)d_in[29];

  char* wsb = (char*)d_ws;
  ushort_t* xsb     = (ushort_t*)(wsb + 0);          //  4096*1152*2 =  9,437,184
  ushort_t* xb      = (ushort_t*)(wsb + 9437184);    //  4096*768*2  =  6,291,456
  ushort_t* wft     = (ushort_t*)(wsb + 15728640);   //  2048*1152*2 =  4,718,592
  ushort_t* w1b     = (ushort_t*)(wsb + 20447232);   //  4*16*1024*2 =    131,072
  ushort_t* bfm     = (ushort_t*)(wsb + 20578304);   //  256*896*2   =    458,752
  float*    biassum = (float*)(wsb + 21037056);      //  256*4       =      1,024
  ushort_t* inter   = (ushort_t*)(wsb + 21038080);   //  4*4096*1024*2 = 33,554,432
  ushort_t* cat     = (ushort_t*)(wsb + 54592512);   //  4096*128*2  =  1,048,576

  k_wprep<<<dim3(10369), dim3(256), 0, stream>>>(
      pWft, miWft, maWft, dWft, pW1, miW1, maW1, dW1,
      pWo, miWo, maWo, dWo, pbo, mibo, mabo, dbo, Wc,
      wft, w1b, bfm, biassum);

  k_xprep<<<dim3(15, 4096), dim3(128), 0, stream>>>(
      x, pawn, minor, major, diag, xsb, xb);

  FtP fp;
  fp.xsb = xsb; fp.wft = wft; fp.inter = inter;
  fp.bft0 = pbft; fp.bft1 = mibft; fp.bft2 = mabft; fp.bft3 = dbft;
  k_ft<<<dim3(16, 32, 4), dim3(256), 0, stream>>>(fp);

  k_w1<<<dim3(32, 4), dim3(256), 0, stream>>>(inter, w1b, cat, pb1, mib1, mab1, db1);

  k_out<<<dim3(4, 32), dim3(256), 0, stream>>>(cat, xb, bfm, biassum, (float*)d_out);
}

// Round 2
// 65.345 us; speedup vs baseline: 1.3152x; 1.3152x over previous
//
#include <hip/hip_runtime.h>

typedef unsigned short ushort_t;
typedef __attribute__((ext_vector_type(8))) __bf16 bf16x8;
typedef __attribute__((ext_vector_type(8))) short short8_t;
typedef __attribute__((ext_vector_type(4))) float f32x4;

#define C127 (127.0f / 128.0f)

__device__ inline ushort_t f2bf(float f) {
  unsigned u = __builtin_bit_cast(unsigned, f);
  u += 0x7fffu + ((u >> 16) & 1u);
  return (ushort_t)(u >> 16);
}

__device__ inline bf16x8 ldfrag(const ushort_t* p) {
  return __builtin_bit_cast(bf16x8, *(const short8_t*)p);
}

__device__ inline f32x4 mfma16(bf16x8 a, bf16x8 b, f32x4 c) {
  return __builtin_amdgcn_mfma_f32_16x16x32_bf16(a, b, c, 0, 0, 0);
}

// logical (row,col) -> position in a 64-wide swizzled tile
__device__ inline int swz(int row, int col) {
  return row * 64 + (col ^ ((row & 7) << 3));
}

// async global->LDS, 16B per lane; lds dest must be wave-uniform base
__device__ inline void gl_lds16(const ushort_t* g, ushort_t* l) {
  __builtin_amdgcn_global_load_lds(
      (const __attribute__((address_space(1))) unsigned*)(g),
      (__attribute__((address_space(3))) unsigned*)(l),
      16, 0, 0);
}

// ---------------- prep: weights -> bf16, pre-swizzled tiled layouts ----------------
// wft_t: per s: [32 rowtiles(64 w-rows)][nk kblks][64x64 swizzled]  (elems)
//   s offsets: 0, 262144, 786432, 1572864
// w1b:   row-major bf16 [4][16][1024]
// bfm_t: [8 nb(32 cols)][14 kblk][32x64 swizzled]
__global__ __launch_bounds__(256) void k_wprep(
    const float* Wp, const float* Wmi, const float* Wma, const float* Wd,
    const float* W1p, const float* W1mi, const float* W1ma, const float* W1d,
    const float* Wop, const float* Womi, const float* Woma, const float* Wod,
    const float* bop, const float* bomi, const float* boma, const float* bod,
    const float* Wc,
    ushort_t* wft, ushort_t* w1b, ushort_t* bfm, float* biassum)
{
  int i = blockIdx.x * 256 + threadIdx.x;
  const int NW = 2359296, NW1 = 65536, NBF = 229376;
  if (i < NW) {
    int jbase, d, nk; const float* src;
    if (i < 262144)       { jbase = 0;       d = 128; nk = 2; src = Wp; }
    else if (i < 786432)  { jbase = 262144;  d = 256; nk = 4; src = Wmi; }
    else if (i < 1572864) { jbase = 786432;  d = 384; nk = 6; src = Wma; }
    else                  { jbase = 1572864; d = 384; nk = 6; src = Wd; }
    int j = i - jbase;
    int tile = j >> 12, e = j & 4095;
    int rowtile = tile / nk, kblk = tile - rowtile * nk;
    int trow = e >> 6, scol = e & 63;
    int col = scol ^ ((trow & 7) << 3);
    wft[i] = f2bf(src[(size_t)(rowtile * 64 + trow) * d + kblk * 64 + col]);
  } else if (i < NW + NW1) {
    int j = i - NW;
    int s = j >> 14, jj = j & 16383;
    const float* src = (s == 0) ? W1p : (s == 1) ? W1mi : (s == 2) ? W1ma : W1d;
    w1b[j] = f2bf(src[jj]);
  } else if (i < NW + NW1 + NBF) {
    int j = i - NW - NW1;
    int tile = j >> 11, e = j & 2047;
    int nb = tile / 14, kblk = tile - nb * 14;
    int trow = e >> 6, scol = e & 63;
    int col = scol ^ ((trow & 7) << 3);
    int n = nb * 32 + trow, c = kblk * 64 + col;
    float v;
    if (c < 128) {
      int s = c >> 5, jj = c & 31;
      const float* src = (s == 0) ? Wop : (s == 1) ? Womi : (s == 2) ? Woma : Wod;
      v = src[n * 32 + jj];
    } else {
      v = Wc[n * 768 + (c - 128)];
    }
    bfm[j] = f2bf(v);
  } else if (i < NW + NW1 + NBF + 256) {
    int n = i - NW - NW1 - NBF;
    biassum[n] = bop[n] + bomi[n] + boma[n] + bod[n];
  }
}

// ---------------- prep: x -> bf16, tiled-swizzled [32 rowblk][12 kblk][128x64] ----------------
__global__ __launch_bounds__(256) void k_xprep(const float* __restrict__ x,
                                               ushort_t* __restrict__ xbt)
{
  int i = blockIdx.x * 256 + threadIdx.x;  // < 3145728
  int tile = i >> 13, e = i & 8191;
  int rowblk = tile / 12, kblk = tile - rowblk * 12;
  int trow = e >> 6, scol = e & 63;
  int col = scol ^ ((trow & 7) << 3);
  xbt[i] = f2bf(x[(size_t)(rowblk * 128 + trow) * 768 + kblk * 64 + col]);
}

// ---------------- ft GEMM + activation + fused W1 partial ----------------
struct FtP {
  const ushort_t* xbt;
  const ushort_t* wft;
  const ushort_t* w1b;
  float* pf;   // [4 s][16 nb][4096 rows][16 j] fp32 partial f
  const float* bft0; const float* bft1; const float* bft2; const float* bft3;
};

__global__ __launch_bounds__(256) void k_ft(FtP p) {
  int s = blockIdx.z;
  int nk, woff; const float* bft; unsigned long long ctbl;
  if (s == 0)      { nk = 2; woff = 0;       bft = p.bft0; ctbl = 0x60ULL; }
  else if (s == 1) { nk = 4; woff = 262144;  bft = p.bft1; ctbl = 0x8721ULL; }
  else if (s == 2) { nk = 6; woff = 786432;  bft = p.bft2; ctbl = 0xBA9543ULL; }
  else             { nk = 6; woff = 1572864; bft = p.bft3; ctbl = 0xBA8542ULL; }

  int rowblk = blockIdx.y; int row0 = rowblk * 128;
  int nb = blockIdx.x;
  int tid = threadIdx.x, lane = tid & 63, wid = tid >> 6;
  int wr = wid >> 1, wc = wid & 1;
  int lr = lane & 15, lk = (lane >> 4) * 8, lrow = (lane >> 4) * 4;

  __shared__ ushort_t lA[128 * 64];
  __shared__ ushort_t lB[2][64 * 64];

  const f32x4 fz = {0.f, 0.f, 0.f, 0.f};
  f32x4 acc[2][4][2];
  for (int h = 0; h < 2; ++h)
    for (int m = 0; m < 4; ++m)
      for (int n = 0; n < 2; ++n) acc[h][m][n] = fz;

  for (int ks = 0; ks < nk; ++ks) {
    int ch = (int)((ctbl >> (4 * ks)) & 15ULL);
    const ushort_t* at  = p.xbt + ((size_t)rowblk * 12 + ch) * 8192;
    const ushort_t* b1t = p.wft + woff + ((size_t)(nb)      * nk + ks) * 4096;
    const ushort_t* b2t = p.wft + woff + ((size_t)(16 + nb) * nk + ks) * 4096;
#pragma unroll
    for (int c = 0; c < 4; ++c) {
      int off = (c * 4 + wid) * 512;
      gl_lds16(at + off + lane * 8, &lA[off]);
    }
#pragma unroll
    for (int c = 0; c < 2; ++c) {
      int off = (c * 4 + wid) * 512;
      gl_lds16(b1t + off + lane * 8, &lB[0][off]);
      gl_lds16(b2t + off + lane * 8, &lB[1][off]);
    }
    __syncthreads();
#pragma unroll
    for (int kk = 0; kk < 64; kk += 32) {
      bf16x8 a[4], b[2][2];
      for (int m = 0; m < 4; ++m)
        a[m] = ldfrag(&lA[swz(wr * 64 + m * 16 + lr, kk + lk)]);
      for (int h = 0; h < 2; ++h)
        for (int n = 0; n < 2; ++n)
          b[h][n] = ldfrag(&lB[h][swz(wc * 32 + n * 16 + lr, kk + lk)]);
      for (int h = 0; h < 2; ++h)
        for (int m = 0; m < 4; ++m)
          for (int n = 0; n < 2; ++n)
            acc[h][m][n] = mfma16(a[m], b[h][n], acc[h][m][n]);
    }
    __syncthreads();
  }

  // epilogue: activation -> LDS (swizzled, reuse lA), then W1 partial via MFMA
  for (int m = 0; m < 4; ++m)
    for (int n = 0; n < 2; ++n) {
      int col = wc * 32 + n * 16 + lr;
      float bb1 = bft[nb * 64 + col];
      float bb2 = bft[1024 + nb * 64 + col];
      for (int r = 0; r < 4; ++r) {
        int row = wr * 64 + m * 16 + lrow + r;
        float v = (acc[0][m][n][r] + bb1) * (acc[1][m][n][r] + bb2) * C127;
        lA[swz(row, col)] = f2bf(v);
      }
    }
  __syncthreads();

  // f_partial[16 rows x 16 j] per wave row-tile; B = W1[j][nb*64 + k]
  const ushort_t* w1base = p.w1b + s * 16384 + lr * 1024 + nb * 64 + lk;
  bf16x8 bw0 = ldfrag(w1base);
  bf16x8 bw1 = ldfrag(w1base + 32);
#pragma unroll
  for (int rt = 0; rt < 2; ++rt) {
    int rowbase = wid * 32 + rt * 16;
    f32x4 af = fz;
    bf16x8 a0 = ldfrag(&lA[swz(rowbase + lr, 0 + lk)]);
    bf16x8 a1 = ldfrag(&lA[swz(rowbase + lr, 32 + lk)]);
    af = mfma16(a0, bw0, af);
    af = mfma16(a1, bw1, af);
    float* pfp = p.pf + ((size_t)(s * 16 + nb) * 4096 + row0 + rowbase + lrow) * 16 + lr;
    for (int r = 0; r < 4; ++r) pfp[r * 16] = af[r];
  }
}

// ---------------- reduce partials -> cat (tiled-swizzled) ----------------
__global__ __launch_bounds__(256) void k_fin(
    const float* __restrict__ pf, ushort_t* __restrict__ cat_t,
    const float* b1p, const float* b1mi, const float* b1ma, const float* b1d)
{
  int tid = threadIdx.x;
  int j = tid & 15, s = (tid >> 4) & 3, rl = tid >> 6;
  int row = blockIdx.x * 4 + rl;
  const float* b1 = (s == 0) ? b1p : (s == 1) ? b1mi : (s == 2) ? b1ma : b1d;
  float acc = 0.f;
  const float* base = pf + (size_t)(s * 16) * 65536 + (size_t)row * 16 + j;
#pragma unroll
  for (int nb = 0; nb < 16; ++nb) acc += base[(size_t)nb * 65536];
  float f = acc + b1[j];
  float cf = fminf(fmaxf(f, 0.f), 1.f);
  float cs = fminf(f * f * C127, 1.f);
  int trow = row & 127, rowblk = row >> 7;
  int c1 = s * 32 + j;
  int kb = c1 >> 6, tc = c1 & 63;
  cat_t[(size_t)(rowblk * 2 + kb) * 8192 + trow * 64 + (tc ^ ((trow & 7) << 3))] = f2bf(cf);
  int c2 = c1 + 16;
  kb = c2 >> 6; tc = c2 & 63;
  cat_t[(size_t)(rowblk * 2 + kb) * 8192 + trow * 64 + (tc ^ ((trow & 7) << 3))] = f2bf(cs);
}

// ---------------- final GEMM: [cat | x] @ [WoAll | Wc]^T + biassum ----------------
__global__ __launch_bounds__(256) void k_out(
    const ushort_t* __restrict__ cat_t, const ushort_t* __restrict__ xbt,
    const ushort_t* __restrict__ bfmt, const float* __restrict__ biassum,
    float* __restrict__ out)
{
  int rowblk = blockIdx.y, row0 = rowblk * 128;
  int nb = blockIdx.x;  // 8 x 32 cols
  int tid = threadIdx.x, lane = tid & 63, wid = tid >> 6;
  int lr = lane & 15, lk = (lane >> 4) * 8, lrow = (lane >> 4) * 4;

  __shared__ ushort_t lA[128 * 64];
  __shared__ ushort_t lB[32 * 64];

  const f32x4 fz = {0.f, 0.f, 0.f, 0.f};
  f32x4 acc[2][2];
  for (int m = 0; m < 2; ++m)
    for (int n = 0; n < 2; ++n) acc[m][n] = fz;

  for (int kb = 0; kb < 14; ++kb) {
    const ushort_t* at = (kb < 2)
        ? cat_t + ((size_t)rowblk * 2 + kb) * 8192
        : xbt + ((size_t)rowblk * 12 + (kb - 2)) * 8192;
    const ushort_t* bt = bfmt + ((size_t)nb * 14 + kb) * 2048;
#pragma unroll
    for (int c = 0; c < 4; ++c) {
      int off = (c * 4 + wid) * 512;
      gl_lds16(at + off + lane * 8, &lA[off]);
    }
    {
      int off = wid * 512;
      gl_lds16(bt + off + lane * 8, &lB[off]);
    }
    __syncthreads();
#pragma unroll
    for (int kk = 0; kk < 64; kk += 32) {
      bf16x8 b0 = ldfrag(&lB[swz(lr, kk + lk)]);
      bf16x8 b1v = ldfrag(&lB[swz(16 + lr, kk + lk)]);
      for (int m = 0; m < 2; ++m) {
        bf16x8 a = ldfrag(&lA[swz(wid * 32 + m * 16 + lr, kk + lk)]);
        acc[m][0] = mfma16(a, b0, acc[m][0]);
        acc[m][1] = mfma16(a, b1v, acc[m][1]);
      }
    }
    __syncthreads();
  }

  for (int m = 0; m < 2; ++m)
    for (int n = 0; n < 2; ++n) {
      int col = nb * 32 + n * 16 + lr;
      float bs = biassum[col];
      for (int r = 0; r < 4; ++r) {
        int row = wid * 32 + m * 16 + lrow + r;
        out[(size_t)(row0 + row) * 256 + col] = acc[m][n][r] + bs;
      }
    }
}

extern "C" void kernel_launch(void* const* d_in, const int* in_sizes, int n_in,
                              void* d_out, int out_size, void* d_ws, size_t ws_size,
                              hipStream_t stream)
{
  const float* x     = (const float*)d_in[0];
  const float* pWft  = (const float*)d_in[5];   const float* pbft  = (const float*)d_in[6];
  const float* pW1   = (const float*)d_in[7];   const float* pb1   = (const float*)d_in[8];
  const float* pWo   = (const float*)d_in[9];   const float* pbo   = (const float*)d_in[10];
  const float* miWft = (const float*)d_in[11];  const float* mibft = (const float*)d_in[12];
  const float* miW1  = (const float*)d_in[13];  const float* mib1  = (const float*)d_in[14];
  const float* miWo  = (const float*)d_in[15];  const float* mibo  = (const float*)d_in[16];
  const float* maWft = (const float*)d_in[17];  const float* mabft = (const float*)d_in[18];
  const float* maW1  = (const float*)d_in[19];  const float* mab1  = (const float*)d_in[20];
  const float* maWo  = (const float*)d_in[21];  const float* mabo  = (const float*)d_in[22];
  const float* dWft  = (const float*)d_in[23];  const float* dbft  = (const float*)d_in[24];
  const float* dW1   = (const float*)d_in[25];  const float* db1   = (const float*)d_in[26];
  const float* dWo   = (const float*)d_in[27];  const float* dbo   = (const float*)d_in[28];
  const float* Wc    = (const float*)d_in[29];

  char* wsb = (char*)d_ws;
  ushort_t* xbt     = (ushort_t*)(wsb + 0);          // 4096*768*2  =  6,291,456
  ushort_t* wft     = (ushort_t*)(wsb + 6291456);    // 2048*1152*2 =  4,718,592
  ushort_t* w1b     = (ushort_t*)(wsb + 11010048);   // 4*16*1024*2 =    131,072
  ushort_t* bfm     = (ushort_t*)(wsb + 11141120);   // 256*896*2   =    458,752
  float*    biassum = (float*)(wsb + 11599872);      // 256*4       =      1,024
  float*    pf      = (float*)(wsb + 11600896);      // 4*16*4096*16*4 = 16,777,216
  ushort_t* cat_t   = (ushort_t*)(wsb + 28378112);   // 4096*128*2  =  1,048,576

  k_wprep<<<dim3(10369), dim3(256), 0, stream>>>(
      pWft, miWft, maWft, dWft, pW1, miW1, maW1, dW1,
      pWo, miWo, maWo, dWo, pbo, mibo, mabo, dbo, Wc,
      wft, w1b, bfm, biassum);

  k_xprep<<<dim3(12288), dim3(256), 0, stream>>>(x, xbt);

  FtP fp;
  fp.xbt = xbt; fp.wft = wft; fp.w1b = w1b; fp.pf = pf;
  fp.bft0 = pbft; fp.bft1 = mibft; fp.bft2 = mabft; fp.bft3 = dbft;
  k_ft<<<dim3(16, 32, 4), dim3(256), 0, stream>>>(fp);

  k_fin<<<dim3(1024), dim3(256), 0, stream>>>(pf, cat_t, pb1, mib1, mab1, db1);

  k_out<<<dim3(8, 32), dim3(256), 0, stream>>>(cat_t, xbt, bfm, biassum, (float*)d_out);
}

// Round 3
// 64.489 us; speedup vs baseline: 1.3327x; 1.0133x over previous
//
#include <hip/hip_runtime.h>

typedef unsigned short ushort_t;
typedef __attribute__((ext_vector_type(8))) __bf16 bf16x8;
typedef __attribute__((ext_vector_type(8))) short short8_t;
typedef __attribute__((ext_vector_type(4))) float f32x4;

#define C127 (127.0f / 128.0f)

__device__ inline ushort_t f2bf(float f) {
  unsigned u = __builtin_bit_cast(unsigned, f);
  u += 0x7fffu + ((u >> 16) & 1u);
  return (ushort_t)(u >> 16);
}

__device__ inline bf16x8 ldfrag(const ushort_t* p) {
  return __builtin_bit_cast(bf16x8, *(const short8_t*)p);
}

__device__ inline f32x4 mfma16(bf16x8 a, bf16x8 b, f32x4 c) {
  return __builtin_amdgcn_mfma_f32_16x16x32_bf16(a, b, c, 0, 0, 0);
}

// swizzle only used for the epilogue LDS exchange
__device__ inline int swz(int row, int col) {
  return row * 64 + (col ^ ((row & 7) << 3));
}

// ============ fused prep: all operands -> bf16 fragment-major ============
// Fragment tile = 16 (rows|cols) x 32 k = 512 elems = 1KB; elem order within
// tile: lane*8+e where lane&15 = row/col, lane>>4 = k-subchunk, e = k&7.
// xbt: [rt 256][kc 24] tiles   (A-frags of x, rt=row/16, kc=k/32)
// wft: per s: [ct][kc nkc] tiles, ct = wcol/16, nkc = d/32
// w1b: row-major [4][16][1024]
// bfm: [ct 16][kc 28] tiles  (B-frags of [WoAll | Wc])
__global__ __launch_bounds__(256) void k_prep(
    const float* __restrict__ x,
    const float* Wp, const float* Wmi, const float* Wma, const float* Wd,
    const float* W1p, const float* W1mi, const float* W1ma, const float* W1d,
    const float* Wop, const float* Womi, const float* Woma, const float* Wod,
    const float* bop, const float* bomi, const float* boma, const float* bod,
    const float* Wc,
    ushort_t* xbt, ushort_t* wft, ushort_t* w1b, ushort_t* bfm, float* biassum)
{
  int i = blockIdx.x * 256 + threadIdx.x;
  const int XCH = 393216, WCH = 294912, W1CH = 8192, BFCH = 28672;
  if (i < XCH) {
    int tile = i >> 6, lane = i & 63;
    int rt = tile / 24, kc = tile - rt * 24;
    int row = rt * 16 + (lane & 15);
    int k = kc * 32 + (lane >> 4) * 8;
    const float* sp = x + (size_t)row * 768 + k;
    ushort_t tmp[8];
#pragma unroll
    for (int e = 0; e < 8; ++e) tmp[e] = f2bf(sp[e]);
    *(short8_t*)(xbt + (size_t)i * 8) = *(const short8_t*)tmp;
  } else if (i < XCH + WCH) {
    int j = i - XCH;
    const float* src; int nkc, d, jj;
    if (j < 32768)       { src = Wp;  nkc = 4;  d = 128; jj = j; }
    else if (j < 98304)  { src = Wmi; nkc = 8;  d = 256; jj = j - 32768; }
    else if (j < 196608) { src = Wma; nkc = 12; d = 384; jj = j - 98304; }
    else                 { src = Wd;  nkc = 12; d = 384; jj = j - 196608; }
    int tile = jj >> 6, lane = jj & 63;
    int ct = tile / nkc, kc = tile - ct * nkc;
    int wcol = ct * 16 + (lane & 15);
    int k = kc * 32 + (lane >> 4) * 8;
    const float* sp = src + (size_t)wcol * d + k;
    ushort_t tmp[8];
#pragma unroll
    for (int e = 0; e < 8; ++e) tmp[e] = f2bf(sp[e]);
    *(short8_t*)(wft + (size_t)j * 8) = *(const short8_t*)tmp;
  } else if (i < XCH + WCH + W1CH) {
    int j = i - XCH - WCH;
    int s = j >> 11, r = j & 2047;
    const float* src = (s == 0) ? W1p : (s == 1) ? W1mi : (s == 2) ? W1ma : W1d;
    ushort_t tmp[8];
#pragma unroll
    for (int e = 0; e < 8; ++e) tmp[e] = f2bf(src[r * 8 + e]);
    *(short8_t*)(w1b + (size_t)j * 8) = *(const short8_t*)tmp;
  } else if (i < XCH + WCH + W1CH + BFCH) {
    int j = i - XCH - WCH - W1CH;
    int tile = j >> 6, lane = j & 63;
    int ct = tile / 28, kc = tile - ct * 28;
    int n = ct * 16 + (lane & 15);
    int c0 = kc * 32 + (lane >> 4) * 8;
    ushort_t tmp[8];
#pragma unroll
    for (int e = 0; e < 8; ++e) {
      int c = c0 + e;
      float v;
      if (c < 128) {
        int ss = c >> 5, jj2 = c & 31;
        const float* src = (ss == 0) ? Wop : (ss == 1) ? Womi : (ss == 2) ? Woma : Wod;
        v = src[n * 32 + jj2];
      } else {
        v = Wc[n * 768 + (c - 128)];
      }
      tmp[e] = f2bf(v);
    }
    *(short8_t*)(bfm + (size_t)j * 8) = *(const short8_t*)tmp;
  } else if (i < XCH + WCH + W1CH + BFCH + 32) {
    int j = i - XCH - WCH - W1CH - BFCH;
#pragma unroll
    for (int e = 0; e < 8; ++e) {
      int n = j * 8 + e;
      biassum[n] = bop[n] + bomi[n] + boma[n] + bod[n];
    }
  }
}

// ============ ft GEMM (barrier-free, fragment streaming) + fused W1 ============
struct FtP {
  const ushort_t* xbt;
  const ushort_t* wft;
  const ushort_t* w1b;
  float* pf;   // [4 s][16 nb][4096 rows][16 j] fp32 partials of f
  const float* bft0; const float* bft1; const float* bft2; const float* bft3;
};

__global__ __launch_bounds__(256) void k_ft(FtP p) {
  int z = blockIdx.z;
  int s = (z == 0) ? 2 : (z == 1) ? 3 : (z == 2) ? 1 : 0;  // long jobs first
  int nk; size_t soff; const float* bft; unsigned long long ctbl;
  if (s == 0)      { nk = 2; soff = 0;       bft = p.bft0; ctbl = 0x60ULL; }
  else if (s == 1) { nk = 4; soff = 262144;  bft = p.bft1; ctbl = 0x8721ULL; }
  else if (s == 2) { nk = 6; soff = 786432;  bft = p.bft2; ctbl = 0xBA9543ULL; }
  else             { nk = 6; soff = 1572864; bft = p.bft3; ctbl = 0xBA8542ULL; }
  int nkc = nk * 2;

  int rowblk = blockIdx.y, row0 = rowblk * 128;
  int nb = blockIdx.x;
  int tid = threadIdx.x, lane = tid & 63, wid = tid >> 6;
  int wr = wid >> 1, wc = wid & 1;
  int lr = lane & 15, lk = (lane >> 4) * 8, lrow = (lane >> 4) * 4;

  __shared__ ushort_t lA[128 * 64];

  // fragment base pointers (per-lane)
  const ushort_t* Ab[4];
#pragma unroll
  for (int m = 0; m < 4; ++m)
    Ab[m] = p.xbt + (size_t)((rowblk * 8 + wr * 4 + m) * 24) * 512 + lane * 8;
  const ushort_t* Bb[2][2];
#pragma unroll
  for (int h = 0; h < 2; ++h)
#pragma unroll
    for (int n = 0; n < 2; ++n)
      Bb[h][n] = p.wft + soff +
                 (size_t)((nb * 4 + wc * 2 + n + h * 64) * nkc) * 512 + lane * 8;

  const f32x4 fz = {0.f, 0.f, 0.f, 0.f};
  f32x4 acc[2][4][2];
#pragma unroll
  for (int h = 0; h < 2; ++h)
#pragma unroll
    for (int m = 0; m < 4; ++m)
#pragma unroll
      for (int n = 0; n < 2; ++n) acc[h][m][n] = fz;

  bf16x8 a0[4], a1[4], b0[2][2], b1[2][2];

#define KCA(t) ((int)((ctbl >> (((t) >> 1) * 4)) & 15ULL) * 2 + ((t) & 1))
#define LOADSET(A, B, t)                                                  \
  {                                                                       \
    int t_ = (t); int kca_ = KCA(t_);                                     \
    _Pragma("unroll") for (int m = 0; m < 4; ++m)                         \
        A[m] = ldfrag(Ab[m] + (size_t)kca_ * 512);                        \
    _Pragma("unroll") for (int h = 0; h < 2; ++h)                         \
        _Pragma("unroll") for (int n = 0; n < 2; ++n)                     \
            B[h][n] = ldfrag(Bb[h][n] + (size_t)t_ * 512);                \
  }
#define MFMASET(A, B)                                                     \
  _Pragma("unroll") for (int h = 0; h < 2; ++h)                           \
      _Pragma("unroll") for (int m = 0; m < 4; ++m)                       \
          _Pragma("unroll") for (int n = 0; n < 2; ++n)                   \
              acc[h][m][n] = mfma16(A[m], B[h][n], acc[h][m][n]);

  LOADSET(a0, b0, 0);
  for (int tt = 0; tt < nk; ++tt) {
    LOADSET(a1, b1, 2 * tt + 1);
    MFMASET(a0, b0);
    int t2 = 2 * tt + 2; if (t2 >= nkc) t2 = nkc - 1;
    LOADSET(a0, b0, t2);
    MFMASET(a1, b1);
  }
#undef LOADSET
#undef MFMASET
#undef KCA

  // epilogue: activation -> LDS (swizzled), W1 partial via MFMA
#pragma unroll
  for (int m = 0; m < 4; ++m)
#pragma unroll
    for (int n = 0; n < 2; ++n) {
      int col = wc * 32 + n * 16 + lr;
      float bb1 = bft[nb * 64 + col];
      float bb2 = bft[1024 + nb * 64 + col];
#pragma unroll
      for (int r = 0; r < 4; ++r) {
        int row = wr * 64 + m * 16 + lrow + r;
        float v = (acc[0][m][n][r] + bb1) * (acc[1][m][n][r] + bb2) * C127;
        lA[swz(row, col)] = f2bf(v);
      }
    }
  __syncthreads();

  const ushort_t* w1base = p.w1b + s * 16384 + lr * 1024 + nb * 64 + lk;
  bf16x8 bw0 = ldfrag(w1base);
  bf16x8 bw1 = ldfrag(w1base + 32);
#pragma unroll
  for (int rt2 = 0; rt2 < 2; ++rt2) {
    int rowbase = wid * 32 + rt2 * 16;
    f32x4 af = {0.f, 0.f, 0.f, 0.f};
    bf16x8 fa0 = ldfrag(&lA[swz(rowbase + lr, 0 + lk)]);
    bf16x8 fa1 = ldfrag(&lA[swz(rowbase + lr, 32 + lk)]);
    af = mfma16(fa0, bw0, af);
    af = mfma16(fa1, bw1, af);
    float* pfp = p.pf + ((size_t)(s * 16 + nb) * 4096 + row0 + rowbase + lrow) * 16 + lr;
#pragma unroll
    for (int r = 0; r < 4; ++r) pfp[r * 16] = af[r];
  }
}

// ============ reduce partials -> cat (fragment-major) ============
__global__ __launch_bounds__(256) void k_fin(
    const float* __restrict__ pf, ushort_t* __restrict__ cat_t,
    const float* b1p, const float* b1mi, const float* b1ma, const float* b1d)
{
  int tid = threadIdx.x;
  int j = tid & 15, s = (tid >> 4) & 3, rl = tid >> 6;
  int row = blockIdx.x * 4 + rl;
  const float* b1 = (s == 0) ? b1p : (s == 1) ? b1mi : (s == 2) ? b1ma : b1d;
  float acc = 0.f;
  const float* base = pf + (size_t)(s * 16) * 65536 + (size_t)row * 16 + j;
#pragma unroll
  for (int nb = 0; nb < 16; ++nb) acc += base[(size_t)nb * 65536];
  float f = acc + b1[j];
  float cf = fminf(fmaxf(f, 0.f), 1.f);
  float cs = fminf(f * f * C127, 1.f);
  int rt = row >> 4, rl16 = row & 15;
  int c1 = s * 32 + j;
  {
    int kc = c1 >> 5, lane2 = rl16 + (((c1 >> 3) & 3) << 4), e = c1 & 7;
    cat_t[(size_t)(rt * 4 + kc) * 512 + lane2 * 8 + e] = f2bf(cf);
  }
  {
    int c2 = c1 + 16;
    int kc = c2 >> 5, lane2 = rl16 + (((c2 >> 3) & 3) << 4), e = c2 & 7;
    cat_t[(size_t)(rt * 4 + kc) * 512 + lane2 * 8 + e] = f2bf(cs);
  }
}

// ============ final GEMM: [cat | x] @ [WoAll|Wc]^T + biassum (barrier-free) ============
__global__ __launch_bounds__(256) void k_out(
    const ushort_t* __restrict__ cat_t, const ushort_t* __restrict__ xbt,
    const ushort_t* __restrict__ bfm, const float* __restrict__ biassum,
    float* __restrict__ out)
{
  int by = blockIdx.y, bx = blockIdx.x;
  int tid = threadIdx.x, lane = tid & 63, wid = tid >> 6;
  int wr = wid >> 1, wc = wid & 1;
  int lr = lane & 15, lrow = (lane >> 4) * 4;

  const ushort_t* Acat[4];
  const ushort_t* Ax[4];
#pragma unroll
  for (int m = 0; m < 4; ++m) {
    int rt = by * 8 + wr * 4 + m;
    Acat[m] = cat_t + (size_t)(rt * 4) * 512 + lane * 8;
    Ax[m]   = xbt + (size_t)(rt * 24) * 512 + lane * 8;
  }
  const ushort_t* Bb[2];
#pragma unroll
  for (int n = 0; n < 2; ++n)
    Bb[n] = bfm + (size_t)((bx * 4 + wc * 2 + n) * 28) * 512 + lane * 8;

  const f32x4 fz = {0.f, 0.f, 0.f, 0.f};
  f32x4 acc[4][2];
#pragma unroll
  for (int m = 0; m < 4; ++m)
#pragma unroll
    for (int n = 0; n < 2; ++n) acc[m][n] = fz;

  bf16x8 a0[4], a1[4], b0[2], b1[2];

#define LOADSET2(A, B, t)                                                  \
  {                                                                        \
    int t_ = (t);                                                          \
    _Pragma("unroll") for (int m = 0; m < 4; ++m)                          \
        A[m] = (t_ < 4) ? ldfrag(Acat[m] + (size_t)t_ * 512)               \
                        : ldfrag(Ax[m] + (size_t)(t_ - 4) * 512);          \
    _Pragma("unroll") for (int n = 0; n < 2; ++n)                          \
        B[n] = ldfrag(Bb[n] + (size_t)t_ * 512);                           \
  }
#define MFMASET2(A, B)                                                     \
  _Pragma("unroll") for (int m = 0; m < 4; ++m)                            \
      _Pragma("unroll") for (int n = 0; n < 2; ++n)                        \
          acc[m][n] = mfma16(A[m], B[n], acc[m][n]);

  LOADSET2(a0, b0, 0);
  for (int tt = 0; tt < 14; ++tt) {
    LOADSET2(a1, b1, 2 * tt + 1);
    MFMASET2(a0, b0);
    int t2 = 2 * tt + 2; if (t2 >= 28) t2 = 27;
    LOADSET2(a0, b0, t2);
    MFMASET2(a1, b1);
  }
#undef LOADSET2
#undef MFMASET2

#pragma unroll
  for (int m = 0; m < 4; ++m)
#pragma unroll
    for (int n = 0; n < 2; ++n) {
      int col = bx * 64 + wc * 32 + n * 16 + lr;
      float bs = biassum[col];
#pragma unroll
      for (int r = 0; r < 4; ++r) {
        int row = by * 128 + wr * 64 + m * 16 + lrow + r;
        out[(size_t)row * 256 + col] = acc[m][n][r] + bs;
      }
    }
}

extern "C" void kernel_launch(void* const* d_in, const int* in_sizes, int n_in,
                              void* d_out, int out_size, void* d_ws, size_t ws_size,
                              hipStream_t stream)
{
  const float* x     = (const float*)d_in[0];
  const float* pWft  = (const float*)d_in[5];   const float* pbft  = (const float*)d_in[6];
  const float* pW1   = (const float*)d_in[7];   const float* pb1   = (const float*)d_in[8];
  const float* pWo   = (const float*)d_in[9];   const float* pbo   = (const float*)d_in[10];
  const float* miWft = (const float*)d_in[11];  const float* mibft = (const float*)d_in[12];
  const float* miW1  = (const float*)d_in[13];  const float* mib1  = (const float*)d_in[14];
  const float* miWo  = (const float*)d_in[15];  const float* mibo  = (const float*)d_in[16];
  const float* maWft = (const float*)d_in[17];  const float* mabft = (const float*)d_in[18];
  const float* maW1  = (const float*)d_in[19];  const float* mab1  = (const float*)d_in[20];
  const float* maWo  = (const float*)d_in[21];  const float* mabo  = (const float*)d_in[22];
  const float* dWft  = (const float*)d_in[23];  const float* dbft  = (const float*)d_in[24];
  const float* dW1   = (const float*)d_in[25];  const float* db1   = (const float*)d_in[26];
  const float* dWo   = (const float*)d_in[27];  const float* dbo   = (const float*)d_in[28];
  const float* Wc    = (const float*)d_in[29];

  char* wsb = (char*)d_ws;
  ushort_t* xbt     = (ushort_t*)(wsb + 0);          // 6,291,456 B
  ushort_t* wft     = (ushort_t*)(wsb + 6291456);    // 4,718,592 B
  ushort_t* w1b     = (ushort_t*)(wsb + 11010048);   //   131,072 B
  ushort_t* bfm     = (ushort_t*)(wsb + 11141120);   //   458,752 B
  float*    biassum = (float*)(wsb + 11599872);      //     1,024 B
  float*    pf      = (float*)(wsb + 11600896);      // 16,777,216 B
  ushort_t* cat_t   = (ushort_t*)(wsb + 28378112);   // 1,048,576 B

  k_prep<<<dim3(2833), dim3(256), 0, stream>>>(
      x, pWft, miWft, maWft, dWft, pW1, miW1, maW1, dW1,
      pWo, miWo, maWo, dWo, pbo, mibo, mabo, dbo, Wc,
      xbt, wft, w1b, bfm, biassum);

  FtP fp;
  fp.xbt = xbt; fp.wft = wft; fp.w1b = w1b; fp.pf = pf;
  fp.bft0 = pbft; fp.bft1 = mibft; fp.bft2 = mabft; fp.bft3 = dbft;
  k_ft<<<dim3(16, 32, 4), dim3(256), 0, stream>>>(fp);

  k_fin<<<dim3(1024), dim3(256), 0, stream>>>(pf, cat_t, pb1, mib1, mab1, db1);

  k_out<<<dim3(4, 32), dim3(256), 0, stream>>>(cat_t, xbt, bfm, biassum, (float*)d_out);
}